// Round 3
// baseline (68.150 us; speedup 1.0000x reference)
//
#include <hip/hip_runtime.h>

typedef __attribute__((ext_vector_type(8))) _Float16 f16x8;
typedef __attribute__((ext_vector_type(16))) float f32x16;
typedef unsigned int uint;

#define NUM 2048
#define SP 12
#define RS 114              // f16 row stride (57 dwords, odd -> bank spread)
#define RSD 57
#define NROW 33
#define CPYB 3762           // 33*114 : copy-B (shift -1 f16) base
#define W16LEN (2*3762 + 64)
#define HROW 29

__global__ __launch_bounds__(64, 2) void simmap_kernel(
    const float* __restrict__ img, const float* __restrict__ img_sr,
    const float* __restrict__ sigma, const int* __restrict__ coords,
    float* __restrict__ out)
{
    __shared__ _Float16 w16[W16LEN];
    __shared__ float hsbuf[NROW*HROW + 8];

    const int n = blockIdx.x;
    const int imgid = blockIdx.y;
    const float* im = imgid ? img_sr : img;
    const int t = threadIdx.x;
    const int r0 = coords[2*n];
    const int c0 = coords[2*n+1];

    // ---- stage: channel-interleaved f16 window w16[r][x*3+c], 2 copies ----
    for (int it = 0; it < 18; ++it) {
        int f = t + it*64;
        if (f < 1089) {
            int r = f / 33, x = f - r*33;
            int ri = r0 + r - 16, ci = c0 + x - 16;
            bool inb = (ri >= 0 && ri < 256 && ci >= 0 && ci < 256);
            int gofs = ri*256 + ci;
            #pragma unroll
            for (int c = 0; c < 3; ++c) {
                float v = inb ? im[c*65536 + gofs] : 0.f;
                _Float16 hv = (_Float16)v;
                int y = 3*x + c;
                w16[r*RS + y] = hv;
                if (y > 0) w16[CPYB + r*RS + y - 1] = hv;   // copyB[z]=content[z+1]
            }
        }
    }
    // zero row pads (finite values everywhere fragments may read)
    for (int it = 0; it < 16; ++it) {
        int f = t + it*64;
        if (f < 1023) {
            int r = f / 31, p = f - r*31;
            if (p < 15) w16[r*RS + 99 + p] = (_Float16)0.f;
            else        w16[CPYB + r*RS + 98 + (p - 15)] = (_Float16)0.f;
        }
    }
    w16[2*CPYB + t] = (_Float16)0.f;   // tail pad
    __syncthreads();

    // ---- hs[r][d1] = sum_c sum_j w16[r][3(d1+j)+c]^2  (f32, from f16) ----
    if (t < 33) {
        const uint* rowp = (const uint*)&w16[t*RS];
        float sq3[33];
        #pragma unroll
        for (int x = 0; x < 33; ++x) {
            int db = (3*x) >> 1;
            union { uint u; _Float16 h2[2]; } A, B;
            A.u = rowp[db]; B.u = rowp[db+1];
            float v0, v1, v2;
            if ((x & 1) == 0) { v0=(float)A.h2[0]; v1=(float)A.h2[1]; v2=(float)B.h2[0]; }
            else              { v0=(float)A.h2[1]; v1=(float)B.h2[0]; v2=(float)B.h2[1]; }
            sq3[x] = v0*v0 + v1*v1 + v2*v2;
        }
        float s = 0.f;
        #pragma unroll
        for (int j = 0; j < 9; ++j) s += sq3[j];
        hsbuf[t*HROW + 0] = s;
        #pragma unroll
        for (int d = 1; d < 25; ++d) { s += sq3[d+8] - sq3[d-1]; hsbuf[t*HROW + d] = s; }
    }
    __syncthreads();

    // ---- A-frag: patch P[i][k], i=lane&31 (rows 9..31 zero), k=16ks+8h+e ----
    const int d1 = t & 31;          // N index (col) for B and C/D
    const int h  = t >> 5;          // k-group
    const bool ivalid = (d1 <= 8);
    const int ieff = ivalid ? d1 : 0;
    f16x8 a0, a1;
    {
        const uint* ap = (const uint*)&w16[(SP + ieff)*RS + 3*SP];
        union { uint u[4]; f16x8 v8; } A0, A1;
        #pragma unroll
        for (int w = 0; w < 4; ++w) { A0.u[w] = ap[4*h + w]; A1.u[w] = ap[8 + 4*h + w]; }
        if (!ivalid) {
            #pragma unroll
            for (int w = 0; w < 4; ++w) { A0.u[w] = 0u; A1.u[w] = 0u; }
        }
        if (h == 1) {               // ks=1,h=1: k=24..31, keep k<=26 (e<=2)
            A1.u[1] &= 0x0000FFFFu; A1.u[2] = 0u; A1.u[3] = 0u;
        }
        a0 = A0.v8; a1 = A1.v8;
    }

    // ---- r-loop: D[i][d1] per window row; accumulate diagonals ----
    float partial[29];
    #pragma unroll
    for (int m = 0; m < 29; ++m) partial[m] = 0.f;

    const int odd = d1 & 1;
    // f16 offset (excl. row term): copyA: 3*d1+8h ; copyB: same-1, +CPYB
    const int bofs = (odd ? (CPYB - 1) : 0) + 3*d1 + 8*h;
    const uint* bp = (const uint*)w16;

    #pragma unroll
    for (int r = 0; r < 33; ++r) {
        const uint* q0 = bp + r*RSD + (bofs >> 1);
        union { uint u[4]; f16x8 v8; } B0, B1;
        #pragma unroll
        for (int w = 0; w < 4; ++w) { B0.u[w] = q0[w]; B1.u[w] = q0[8 + w]; }
        f32x16 D = {0.f,0.f,0.f,0.f,0.f,0.f,0.f,0.f,0.f,0.f,0.f,0.f,0.f,0.f,0.f,0.f};
        D = __builtin_amdgcn_mfma_f32_32x32x16_f16(a0, B0.v8, D, 0, 0, 0);
        D = __builtin_amdgcn_mfma_f32_32x32x16_f16(a1, B1.v8, D, 0, 0, 0);
        // row i = (reg&3) + 8*(reg>>2) + 4h ; partial[m = d0+4h = r-reg]
        if (r     <= 28)             partial[r  ] += D[0];
        if (r >= 1 && r - 1 <= 28)   partial[r-1] += D[1];
        if (r >= 2 && r - 2 <= 28)   partial[r-2] += D[2];
        if (r >= 3 && r - 3 <= 28)   partial[r-3] += D[3];
        if (r >= 8 && r - 8 <= 28)   partial[r-8] += D[4];   // i=8+4h (h=1 adds 0)
    }

    // ---- epilogue: ssd = bs + cc - 2*cross ; out = exp(ssd*scale) ----
    const float sg = fmaxf(sigma[0], 0.f);
    const float scl = -1.f / (243.f * sg);

    float cc = 0.f;
    #pragma unroll
    for (int i = 0; i < 9; ++i) cc += hsbuf[(SP + i)*HROW + SP];

    float ring[9];
    float bs = 0.f;
    #pragma unroll
    for (int i = 0; i < 9; ++i) { ring[i] = hsbuf[i*HROW + d1]; bs += ring[i]; }

    float* op = out + ((size_t)(imgid*NUM + n)) * 625;
    #pragma unroll
    for (int d0 = 0; d0 < 25; ++d0) {
        float v = h ? partial[d0 + 4] : partial[d0];
        float wv = __shfl_xor(v, 32, 64);
        float cross = v + wv;
        float ssd = bs + cc - 2.f * cross;
        float o = __expf(ssd * scl + 1e-20f);
        if (h == 0 && d1 < 25) op[d0*25 + d1] = o;
        if (d0 < 24) {
            float nv = hsbuf[(d0 + 9)*HROW + d1];
            bs += nv - ring[d0 % 9];
            ring[d0 % 9] = nv;
        }
    }
}

extern "C" void kernel_launch(void* const* d_in, const int* in_sizes, int n_in,
                              void* d_out, int out_size, void* d_ws, size_t ws_size,
                              hipStream_t stream) {
    const float* img    = (const float*)d_in[0];
    const float* img_sr = (const float*)d_in[1];
    const float* sigma  = (const float*)d_in[2];
    const int*   coords = (const int*)d_in[3];
    float* out = (float*)d_out;
    dim3 grid(NUM, 2);
    simmap_kernel<<<grid, dim3(64), 0, stream>>>(img, img_sr, sigma, coords, out);
}

// Round 4
// 44.052 us; speedup vs baseline: 1.5470x; 1.5470x over previous
//
#include <hip/hip_runtime.h>

typedef unsigned int uint;

#define NUM 2048
#define SP 12
#define WIN 33
#define ARS 40   // copyA row stride, f16 units (80B: 16B-aligned rows, 5-chunk bank spread)
#define BRS 24   // copyB row stride, f16 units (48B: 16B-aligned, 3-chunk spread)
#define HROW 28

union F16P { uint u; _Float16 h[2]; };
__device__ __forceinline__ float f16lo(uint u){ F16P p; p.u=u; return (float)p.h[0]; }
__device__ __forceinline__ float f16hi(uint u){ F16P p; p.u=u; return (float)p.h[1]; }

__global__ __launch_bounds__(128, 2) void simmap_kernel(
    const float* __restrict__ img, const float* __restrict__ img_sr,
    const float* __restrict__ sigma, const int* __restrict__ coords,
    float* __restrict__ out)
{
    __shared__ __align__(16) _Float16 wa[3*WIN*ARS];  // window floats 0..32 per row
    __shared__ __align__(16) _Float16 wb[3*WIN*BRS];  // window floats 12..32 per row
    __shared__ __align__(16) float hs[WIN*HROW];
    __shared__ __align__(16) float part[50*13];

    const int n = blockIdx.x;
    const int imgid = blockIdx.y;
    const float* im = imgid ? img_sr : img;
    const int t = threadIdx.x;
    const int w = t >> 6;
    const int l = t & 63;
    const int r0 = coords[2*n];
    const int c0 = coords[2*n+1];

    // ---- stage f16 window, two shifted copies ----
    if (r0 >= 16 && r0 < 240 && c0 >= 16 && c0 < 240) {
        const float* base = im + (r0-16)*256 + (c0-16);
        for (int f = t; f < WIN*WIN; f += 128) {
            int r = f / WIN, x = f - r*WIN;
            int go = r*256 + x;
            #pragma unroll
            for (int c = 0; c < 3; ++c) {
                _Float16 hv = (_Float16)base[c*65536 + go];
                wa[(c*WIN + r)*ARS + x] = hv;
                if (x >= SP) wb[(c*WIN + r)*BRS + (x - SP)] = hv;
            }
        }
    } else {
        for (int f = t; f < WIN*WIN; f += 128) {
            int r = f / WIN, x = f - r*WIN;
            int ri = r0 + r - 16, ci = c0 + x - 16;
            bool inb = (ri >= 0 && ri < 256 && ci >= 0 && ci < 256);
            int go = ri*256 + ci;
            #pragma unroll
            for (int c = 0; c < 3; ++c) {
                float v = inb ? im[c*65536 + go] : 0.f;
                _Float16 hv = (_Float16)v;
                wa[(c*WIN + r)*ARS + x] = hv;
                if (x >= SP) wb[(c*WIN + r)*BRS + (x - SP)] = hv;
            }
        }
    }
    __syncthreads();

    // ---- hs[r][d1] = sum_c sum_j w[c][r][d1+j]^2 (wave0, lanes<33) ----
    if (w == 0 && l < WIN) {
        float sq3[33];
        #pragma unroll
        for (int x = 0; x < 33; ++x) sq3[x] = 0.f;
        #pragma unroll 1
        for (int c = 0; c < 3; ++c) {
            const uint* rp = (const uint*)&wa[(c*WIN + l)*ARS];
            uint U[17];
            #pragma unroll
            for (int q = 0; q < 4; ++q) {
                uint4 v = ((const uint4*)rp)[q];
                U[4*q+0]=v.x; U[4*q+1]=v.y; U[4*q+2]=v.z; U[4*q+3]=v.w;
            }
            U[16] = rp[16];
            #pragma unroll
            for (int x = 0; x < 33; ++x) {
                float v = (x & 1) ? f16hi(U[x>>1]) : f16lo(U[x>>1]);
                sq3[x] += v*v;
            }
        }
        float s = 0.f;
        #pragma unroll
        for (int j = 0; j < 9; ++j) s += sq3[j];
        hs[l*HROW + 0] = s;
        #pragma unroll
        for (int d = 1; d < 25; ++d) { s += sq3[d+8] - sq3[d-1]; hs[l*HROW + d] = s; }
    }

    // ---- cross term ----
    const int d0 = l >> 1;
    const int half = l & 1;
    const int d0e = (l < 50) ? d0 : 0;
    float cr[13];
    #pragma unroll
    for (int o = 0; o < 13; ++o) cr[o] = 0.f;

    auto ROW = [&](int c, int i) {
        const uint* q = half ? (const uint*)&wb[(c*WIN + d0e + i)*BRS]
                             : (const uint*)&wa[(c*WIN + d0e + i)*ARS];
        uint U[11];
        uint4 v0 = *(const uint4*)q;
        uint4 v1 = *(const uint4*)(q + 4);
        uint2 v2 = *(const uint2*)(q + 8);
        U[0]=v0.x; U[1]=v0.y; U[2]=v0.z; U[3]=v0.w;
        U[4]=v1.x; U[5]=v1.y; U[6]=v1.z; U[7]=v1.w;
        U[8]=v2.x; U[9]=v2.y; U[10]=q[10];
        float rv[21];
        #pragma unroll
        for (int x = 0; x < 21; ++x)
            rv[x] = (x & 1) ? f16hi(U[x>>1]) : f16lo(U[x>>1]);
        const uint* cp = (const uint*)&wb[(c*WIN + SP + i)*BRS];  // center row, floats 12..
        uint4 cv = *(const uint4*)cp; uint cv1 = cp[4];
        float cw[9] = {f16lo(cv.x),f16hi(cv.x),f16lo(cv.y),f16hi(cv.y),
                       f16lo(cv.z),f16hi(cv.z),f16lo(cv.w),f16hi(cv.w),f16lo(cv1)};
        #pragma unroll
        for (int j = 0; j < 9; ++j)
            #pragma unroll
            for (int o = 0; o < 13; ++o)
                cr[o] = fmaf(rv[o + j], cw[j], cr[o]);
    };

    // wave0: c=0 (9 rows) + c=2 i=0..1  (11 rows; also owns hs+epilogue)
    // wave1: c=1 (9 rows) + c=2 i=2..8  (16 rows)
    {
        const int cA = w;
        #pragma unroll 1
        for (int i = 0; i < 9; ++i) ROW(cA, i);
        const int ib = w ? 2 : 0;
        const int ie = w ? 9 : 2;
        #pragma unroll 1
        for (int i = ib; i < ie; ++i) ROW(2, i);
    }

    if (w == 1 && l < 50) {
        #pragma unroll
        for (int o = 0; o < 13; ++o) part[l*13 + o] = cr[o];
    }
    __syncthreads();
    if (w == 1 || l >= 50) return;

    // ---- epilogue (wave0, lanes<50) ----
    #pragma unroll
    for (int o = 0; o < 13; ++o) cr[o] += part[l*13 + o];

    const int d1b = half * 12;
    float cc = 0.f;
    #pragma unroll
    for (int i = 0; i < 9; ++i) cc += hs[(SP + i)*HROW + SP];

    float bs[13];
    #pragma unroll
    for (int o = 0; o < 13; ++o) bs[o] = 0.f;
    #pragma unroll
    for (int i = 0; i < 9; ++i) {
        const float* hr = &hs[(d0 + i)*HROW + d1b];
        float4 a = *(const float4*)hr;
        float4 b = *(const float4*)(hr + 4);
        float4 d2 = *(const float4*)(hr + 8);
        float hv[13] = {a.x,a.y,a.z,a.w,b.x,b.y,b.z,b.w,d2.x,d2.y,d2.z,d2.w,hr[12]};
        #pragma unroll
        for (int o = 0; o < 13; ++o) bs[o] += hv[o];
    }

    const float sg = fmaxf(sigma[0], 0.f);
    const float scl = -1.f / (243.f * sg);
    float* op = out + (size_t)(imgid*NUM + n)*625 + d0*25 + d1b;
    #pragma unroll
    for (int o = 0; o < 13; ++o)
        op[o] = __expf((bs[o] + cc - 2.f*cr[o]) * scl + 1e-20f);
}

extern "C" void kernel_launch(void* const* d_in, const int* in_sizes, int n_in,
                              void* d_out, int out_size, void* d_ws, size_t ws_size,
                              hipStream_t stream) {
    const float* img    = (const float*)d_in[0];
    const float* img_sr = (const float*)d_in[1];
    const float* sigma  = (const float*)d_in[2];
    const int*   coords = (const int*)d_in[3];
    float* out = (float*)d_out;
    dim3 grid(NUM, 2);
    simmap_kernel<<<grid, dim3(128), 0, stream>>>(img, img_sr, sigma, coords, out);
}